// Round 2
// baseline (10682.917 us; speedup 1.0000x reference)
//
#include <hip/hip_runtime.h>
#include <stdint.h>
#include <stddef.h>

// ---------------- problem constants ----------------
#define B_   64
#define L_   512
#define E_   512
#define HL_  1024
#define HS_  256
#define NC_  5
#define KL_  (E_ + HL_)   // 1536  concat K for large cell
#define KS_  (E_ + HS_)   // 768   concat K for small cell
#define ROWS_L_ 4096      // 4*HL
#define ROWS_S_ 1024      // 4*HS
#define ROWS_TOT_ 5120
#define SL_  8            // K-slices large (192 each = 6 ksteps of 32)
#define SS_  4            // K-slices small (192 each)

typedef __attribute__((ext_vector_type(8))) short bf16x8;   // 8 bf16 in 4 VGPRs
typedef __attribute__((ext_vector_type(4))) float f32x4;

__device__ __forceinline__ uint16_t f2bf(float f) {
  union { float f; uint32_t u; } v; v.f = f;
  uint32_t r = v.u + 0x7FFFu + ((v.u >> 16) & 1u);
  return (uint16_t)(r >> 16);
}
__device__ __forceinline__ float bf2f(uint16_t h) {
  union { uint32_t u; float f; } v; v.u = ((uint32_t)h) << 16; return v.f;
}
__device__ __forceinline__ float sigm(float x) { return 1.0f / (1.0f + expf(-x)); }

// ---------------- setup kernels ----------------

// Build bf16 hi/lo concatenated weights: Wl[4096][1536] = [W_ih_l | W_hh_l],
// Ws[1024][768] = [W_ih_s | W_hh_s].  lo = round(v - hi) captures next 8 bits.
__global__ __launch_bounds__(256) void k_convw(
    const float* __restrict__ Wihl, const float* __restrict__ Whhl,
    const float* __restrict__ Wihs, const float* __restrict__ Whhs,
    uint16_t* __restrict__ Wl_hi, uint16_t* __restrict__ Wl_lo,
    uint16_t* __restrict__ Ws_hi, uint16_t* __restrict__ Ws_lo) {
  const int N1 = ROWS_L_ * KL_;          // 6291456
  const int N2 = ROWS_S_ * KS_;          // 786432
  int idx = blockIdx.x * 256 + threadIdx.x;
  if (idx < N1) {
    int row = idx / KL_, k = idx - row * KL_;
    float v = (k < E_) ? Wihl[row * E_ + k] : Whhl[row * HL_ + (k - E_)];
    uint16_t hi = f2bf(v);
    Wl_hi[idx] = hi;
    Wl_lo[idx] = f2bf(v - bf2f(hi));
  } else if (idx < N1 + N2) {
    int j = idx - N1;
    int row = j / KS_, k = j - row * KS_;
    float v = (k < E_) ? Wihs[row * E_ + k] : Whhs[row * HS_ + (k - E_)];
    uint16_t hi = f2bf(v);
    Ws_hi[j] = hi;
    Ws_lo[j] = f2bf(v - bf2f(hi));
  }
}

// Gather embedding rows into bf16 hi/lo: A[t][b][k]
__global__ __launch_bounds__(256) void k_embed(
    const int* __restrict__ x, const float* __restrict__ emb,
    uint16_t* __restrict__ Ahi, uint16_t* __restrict__ Alo) {
  int idx = blockIdx.x * 256 + threadIdx.x;       // < L*B*E = 16.7M
  int t = idx >> 15;                               // /(B*E)
  int rem = idx & 32767;
  int b = rem >> 9;                                // /E
  int k = rem & 511;
  int tok = x[b * L_ + t];
  float v = emb[(size_t)tok * E_ + k];
  uint16_t hi = f2bf(v);
  Ahi[idx] = hi;
  Alo[idx] = f2bf(v - bf2f(hi));
}

// Zero the state block — ws is poisoned 0xAA.
__global__ __launch_bounds__(256) void k_zero(uint32_t* __restrict__ p, int nwords) {
  int idx = blockIdx.x * 256 + threadIdx.x;
  if (idx < nwords) p[idx] = 0u;
}

// r_seq[t][b][2] = softmax(-log(-log(u)))   (tau = 1; p_t faithfully unused)
__global__ __launch_bounds__(256) void k_rseq(
    const float* __restrict__ gum, float* __restrict__ rseq) {
  int idx = blockIdx.x * 256 + threadIdx.x;       // t*64+b
  int t = idx >> 6, b = idx & 63;
  float u0 = gum[(b * L_ + t) * 2 + 0];
  float u1 = gum[(b * L_ + t) * 2 + 1];
  float g0 = -logf(-logf(u0));
  float g1 = -logf(-logf(u1));
  float m = fmaxf(g0, g1);
  float e0 = expf(g0 - m), e1 = expf(g1 - m);
  float inv = 1.0f / (e0 + e1);
  rseq[idx * 2 + 0] = e0 * inv;
  rseq[idx * 2 + 1] = e1 * inv;
}

// Pe[t][b][j] = e_t[b] . W_p[j][0:512]  computed from fp32 emb (exact)
__global__ __launch_bounds__(256) void k_pe(
    const int* __restrict__ x, const float* __restrict__ emb,
    const float* __restrict__ Wp, float* __restrict__ Pe) {
  int idx = blockIdx.x * 256 + threadIdx.x;       // t*64+b
  int t = idx >> 6, b = idx & 63;
  int tok = x[b * L_ + t];
  const float* row = emb + (size_t)tok * E_;
  float a0 = 0.f, a1 = 0.f;
  for (int k = 0; k < E_; ++k) {
    float e = row[k];
    a0 += e * Wp[k];
    a1 += e * Wp[(E_ + 2 * HL_) + k];
  }
  Pe[idx * 2 + 0] = a0;
  Pe[idx * 2 + 1] = a1;
}

// ---------------- per-step kernel A: K-sliced 3-term split-bf16 MFMA GEMM ----
// acc += Ahi.Whi + Alo.Whi + Ahi.Wlo   (fp32-accurate to ~2^-16 rel)
// blocks 0..511  : large cell, rowtile rt=bid>>3 (64 rows), slice s=bid&7
// blocks 512..575: small cell, rowtile rt (64 rows), slice s=bid&3
__global__ __launch_bounds__(64) void k_step_gemm(
    const uint16_t* __restrict__ Ahi, const uint16_t* __restrict__ Alo,
    const uint16_t* __restrict__ h_hi, const uint16_t* __restrict__ h_lo,
    const uint16_t* __restrict__ hs_hi, const uint16_t* __restrict__ hs_lo,
    const uint16_t* __restrict__ Wl_hi, const uint16_t* __restrict__ Wl_lo,
    const uint16_t* __restrict__ Ws_hi, const uint16_t* __restrict__ Ws_lo,
    float* __restrict__ partial, int t) {
  int bid = blockIdx.x;
  int lane = threadIdx.x;
  int quad = lane >> 4, l16 = lane & 15;
  const uint16_t* actE_hi = Ahi + (size_t)t * (B_ * E_);
  const uint16_t* actE_lo = Alo + (size_t)t * (B_ * E_);
  const uint16_t *actH_hi, *actH_lo, *W_hi, *W_lo;
  int r0, s, wstride, hstride, rbase;
  if (bid < 512) {
    int rt = bid >> 3; s = bid & 7;
    r0 = rt * 64; W_hi = Wl_hi; W_lo = Wl_lo; wstride = KL_;
    actH_hi = h_hi; actH_lo = h_lo; hstride = HL_; rbase = 0;
  } else {
    int b2 = bid - 512;
    int rt = b2 >> 2; s = b2 & 3;
    r0 = rt * 64; W_hi = Ws_hi; W_lo = Ws_lo; wstride = KS_;
    actH_hi = hs_hi; actH_lo = hs_lo; hstride = HS_; rbase = ROWS_L_;
  }
  int k0 = s * 192;

  f32x4 acc[4][4];
#pragma unroll
  for (int mt = 0; mt < 4; ++mt)
#pragma unroll
    for (int nt = 0; nt < 4; ++nt) {
      acc[mt][nt][0] = 0.f; acc[mt][nt][1] = 0.f;
      acc[mt][nt][2] = 0.f; acc[mt][nt][3] = 0.f;
    }

  int ko = quad * 8;
#pragma unroll
  for (int kk = 0; kk < 6; ++kk) {
    int kbase = k0 + kk * 32;
    bf16x8 a_hi[4], a_lo[4], b_hi[4], b_lo[4];
#pragma unroll
    for (int mt = 0; mt < 4; ++mt) {
      int m = mt * 16 + l16;  // batch
      const uint16_t* phi;
      const uint16_t* plo;
      if (kbase < E_) {
        phi = actE_hi + m * E_ + kbase;
        plo = actE_lo + m * E_ + kbase;
      } else {
        phi = actH_hi + m * hstride + (kbase - E_);
        plo = actH_lo + m * hstride + (kbase - E_);
      }
      a_hi[mt] = *reinterpret_cast<const bf16x8*>(phi + ko);
      a_lo[mt] = *reinterpret_cast<const bf16x8*>(plo + ko);
    }
#pragma unroll
    for (int nt = 0; nt < 4; ++nt) {
      int n = r0 + nt * 16 + l16;  // gate row
      b_hi[nt] = *reinterpret_cast<const bf16x8*>(W_hi + (size_t)n * wstride + kbase + ko);
      b_lo[nt] = *reinterpret_cast<const bf16x8*>(W_lo + (size_t)n * wstride + kbase + ko);
    }
#pragma unroll
    for (int mt = 0; mt < 4; ++mt)
#pragma unroll
      for (int nt = 0; nt < 4; ++nt) {
        acc[mt][nt] = __builtin_amdgcn_mfma_f32_16x16x32_bf16(a_hi[mt], b_hi[nt], acc[mt][nt], 0, 0, 0);
        acc[mt][nt] = __builtin_amdgcn_mfma_f32_16x16x32_bf16(a_lo[mt], b_hi[nt], acc[mt][nt], 0, 0, 0);
        acc[mt][nt] = __builtin_amdgcn_mfma_f32_16x16x32_bf16(a_hi[mt], b_lo[nt], acc[mt][nt], 0, 0, 0);
      }
  }

  // D layout: m(batch) = quad*4+reg, n(gate row) = l16
#pragma unroll
  for (int mt = 0; mt < 4; ++mt)
#pragma unroll
    for (int nt = 0; nt < 4; ++nt)
#pragma unroll
      for (int r = 0; r < 4; ++r) {
        int b = mt * 16 + quad * 4 + r;
        int row = rbase + r0 + nt * 16 + l16;
        partial[((size_t)s * B_ + b) * ROWS_TOT_ + row] = acc[mt][nt][r];
      }
}

// ---------------- per-step kernel B: reduce + pointwise + blend + p ----------------
__global__ __launch_bounds__(256) void k_step_point(
    const float* __restrict__ partial, float* __restrict__ c_l,
    float* __restrict__ h_f, uint16_t* __restrict__ h_hi, uint16_t* __restrict__ h_lo,
    float* __restrict__ c_s, uint16_t* __restrict__ hs_hi, uint16_t* __restrict__ hs_lo,
    float* __restrict__ p_acc, const float* __restrict__ rseq,
    const float* __restrict__ bihl, const float* __restrict__ bhhl,
    const float* __restrict__ bihs, const float* __restrict__ bhhs,
    const float* __restrict__ Wp, float* __restrict__ out_h, int t) {
  int bb = blockIdx.x >> 2, cc = blockIdx.x & 3;
  int tid = threadIdx.x;
  int d = cc * 256 + tid;

  // large cell gates (i,f,g,o)
  float g4[4];
#pragma unroll
  for (int g = 0; g < 4; ++g) {
    int row = g * HL_ + d;
    float v = bihl[row] + bhhl[row];
#pragma unroll
    for (int s = 0; s < SL_; ++s)
      v += partial[((size_t)s * B_ + bb) * ROWS_TOT_ + row];
    g4[g] = v;
  }
  float cprev = c_l[bb * HL_ + d];
  float cn = sigm(g4[1]) * cprev + sigm(g4[0]) * tanhf(g4[2]);
  float hn = sigm(g4[3]) * tanhf(cn);

  // small cell (only d<256 chunk)
  float hs_new = 0.f, cs_new = 0.f;
  if (cc == 0) {
    float gs[4];
#pragma unroll
    for (int g = 0; g < 4; ++g) {
      int row = ROWS_L_ + g * HS_ + d;
      float v = bihs[g * HS_ + d] + bhhs[g * HS_ + d];
#pragma unroll
      for (int s = 0; s < SS_; ++s)
        v += partial[((size_t)s * B_ + bb) * ROWS_TOT_ + row];
      gs[g] = v;
    }
    float csp = c_s[bb * HS_ + d];
    cs_new = sigm(gs[1]) * csp + sigm(gs[0]) * tanhf(gs[2]);
    hs_new = sigm(gs[3]) * tanhf(cs_new);
    c_s[bb * HS_ + d] = cs_new;
    uint16_t hi = f2bf(hs_new);
    hs_hi[bb * HS_ + d] = hi;
    hs_lo[bb * HS_ + d] = f2bf(hs_new - bf2f(hi));
  }

  // blend (r depends only on u — precomputed)
  float r0v = rseq[(t * B_ + bb) * 2 + 0];
  float r1v = rseq[(t * B_ + bb) * 2 + 1];
  float hb = (cc == 0) ? hs_new : h_f[bb * HL_ + d];   // tail = prev carry h
  float cb = (cc == 0) ? cs_new : cn;                  // tail = c_l_new
  float hnext = r0v * hn + r1v * hb;
  float cnext = r0v * cn + r1v * cb;

  c_l[bb * HL_ + d] = cnext;
  h_f[bb * HL_ + d] = hnext;
  uint16_t hhi = f2bf(hnext);
  h_hi[bb * HL_ + d] = hhi;
  h_lo[bb * HL_ + d] = f2bf(hnext - bf2f(hhi));
  out_h[((size_t)bb * L_ + t) * HL_ + d] = hnext;      // h_stack[b][t][d]

  // p_t partials over the h/c part: p[j] += hn*Wp[j][512+d] + cn*Wp[j][1536+d]
  float p0 = hn * Wp[E_ + d] + cn * Wp[E_ + HL_ + d];
  float p1 = hn * Wp[(E_ + 2 * HL_) + E_ + d] + cn * Wp[(E_ + 2 * HL_) + E_ + HL_ + d];
  __shared__ float s0[256], s1[256];
  s0[tid] = p0; s1[tid] = p1;
  __syncthreads();
  for (int off = 128; off > 0; off >>= 1) {
    if (tid < off) { s0[tid] += s0[tid + off]; s1[tid] += s1[tid + off]; }
    __syncthreads();
  }
  if (tid == 0) {
    atomicAdd(&p_acc[(t * B_ + bb) * 2 + 0], s0[0]);
    atomicAdd(&p_acc[(t * B_ + bb) * 2 + 1], s1[0]);
  }
}

// ---------------- final kernels ----------------

__global__ __launch_bounds__(256) void k_cls1(
    const float* __restrict__ h_f, const float* __restrict__ Wc1,
    const float* __restrict__ bc1, float* __restrict__ z1) {
  int idx = blockIdx.x * 256 + threadIdx.x;  // < 64*512
  int b = idx >> 9, j = idx & 511;
  float s = bc1[j];
  const float* hr = h_f + b * HL_;
  const float* wr = Wc1 + (size_t)j * HL_;
  for (int d = 0; d < HL_; ++d) s += fmaxf(hr[d], 0.f) * wr[d];
  z1[idx] = fmaxf(s, 0.f);
}

__global__ __launch_bounds__(64) void k_cls2(
    const float* __restrict__ z1, const float* __restrict__ Wc2,
    const float* __restrict__ bc2, float* __restrict__ out) {
  int b = blockIdx.x;
  int tid = threadIdx.x;
  __shared__ float sv[NC_];
  if (tid < NC_) {
    float s = bc2[tid];
    const float* zr = z1 + b * 512;
    const float* wr = Wc2 + tid * 512;
    for (int k = 0; k < 512; ++k) s += zr[k] * wr[k];
    sv[tid] = s;
  }
  __syncthreads();
  if (tid == 0) {
    float m = sv[0];
    for (int j = 1; j < NC_; ++j) m = fmaxf(m, sv[j]);
    float e[NC_], sum = 0.f;
    for (int j = 0; j < NC_; ++j) { e[j] = expf(sv[j] - m); sum += e[j]; }
    float inv = 1.0f / sum;
    for (int j = 0; j < NC_; ++j) out[b * NC_ + j] = e[j] * inv;
  }
}

__global__ __launch_bounds__(256) void k_pfinal(
    const float* __restrict__ p_acc, const float* __restrict__ Pe,
    const float* __restrict__ bp, float* __restrict__ out_p) {
  int idx = blockIdx.x * 256 + threadIdx.x;  // b*512+t
  int b = idx >> 9, t = idx & 511;
  int i2 = (t * B_ + b) * 2;
  float v0 = p_acc[i2 + 0] + Pe[i2 + 0] + bp[0];
  float v1 = p_acc[i2 + 1] + Pe[i2 + 1] + bp[1];
  float m = fmaxf(v0, v1);
  float e0 = expf(v0 - m), e1 = expf(v1 - m);
  float inv = 1.0f / (e0 + e1);
  out_p[(size_t)idx * 2 + 0] = e0 * inv;
  out_p[(size_t)idx * 2 + 1] = e1 * inv;
}

// ---------------- host ----------------
extern "C" void kernel_launch(void* const* d_in, const int* in_sizes, int n_in,
                              void* d_out, int out_size, void* d_ws, size_t ws_size,
                              hipStream_t stream) {
  const int*   x    = (const int*)d_in[0];
  const float* gum  = (const float*)d_in[1];
  const float* emb  = (const float*)d_in[2];
  const float* Wihl = (const float*)d_in[3];
  const float* Whhl = (const float*)d_in[4];
  const float* bihl = (const float*)d_in[5];
  const float* bhhl = (const float*)d_in[6];
  const float* Wihs = (const float*)d_in[7];
  const float* Whhs = (const float*)d_in[8];
  const float* bihs = (const float*)d_in[9];
  const float* bhhs = (const float*)d_in[10];
  const float* Wp   = (const float*)d_in[11];
  const float* bp   = (const float*)d_in[12];
  const float* Wc1  = (const float*)d_in[13];
  const float* bc1  = (const float*)d_in[14];
  const float* Wc2  = (const float*)d_in[15];
  const float* bc2  = (const float*)d_in[16];
  float* out = (float*)d_out;

  char* ws = (char*)d_ws;
  // workspace layout (bytes) — ~108 MB total
  uint16_t* Ahi   = (uint16_t*)(ws + 0);           //  33,554,432  [L][B][E]
  uint16_t* Alo   = (uint16_t*)(ws + 33554432);    //  33,554,432
  uint16_t* Wl_hi = (uint16_t*)(ws + 67108864);    //  12,582,912  [4096][1536]
  uint16_t* Wl_lo = (uint16_t*)(ws + 79691776);    //  12,582,912
  uint16_t* Ws_hi = (uint16_t*)(ws + 92274688);    //   1,572,864  [1024][768]
  uint16_t* Ws_lo = (uint16_t*)(ws + 93847552);    //   1,572,864
  float*    part  = (float*)   (ws + 95420416);    //  10,485,760  [8][64][5120]
  // state block (zeroed): 105,906,176 ..
  float*    c_l   = (float*)   (ws + 105906176);   //     262,144
  float*    h_f   = (float*)   (ws + 106168320);   //     262,144
  float*    c_s   = (float*)   (ws + 106430464);   //      65,536
  float*    p_acc = (float*)   (ws + 106496000);   //     262,144  [L][B][2]
  uint16_t* h_hi  = (uint16_t*)(ws + 106758144);   //     131,072
  uint16_t* h_lo  = (uint16_t*)(ws + 106889216);   //     131,072
  uint16_t* hs_hi = (uint16_t*)(ws + 107020288);   //      32,768
  uint16_t* hs_lo = (uint16_t*)(ws + 107053056);   //      32,768
  float*    Pe    = (float*)   (ws + 107085824);   //     262,144  [L][B][2]
  float*    rseq  = (float*)   (ws + 107347968);   //     262,144  [L][B][2]
  float*    z1    = (float*)   (ws + 107610112);   //     131,072  [64][512]

  float* out_logits = out;                          // 320
  float* out_h      = out + 320;                    // [B][L][HL]
  float* out_p      = out + 320 + (size_t)B_ * L_ * HL_;  // [B][L][2]

  // ---- setup ----
  {
    int n = ROWS_L_ * KL_ + ROWS_S_ * KS_;  // 7,077,888
    k_convw<<<(n + 255) / 256, 256, 0, stream>>>(Wihl, Whhl, Wihs, Whhs,
                                                 Wl_hi, Wl_lo, Ws_hi, Ws_lo);
  }
  k_embed<<<(L_ * B_ * E_) / 256, 256, 0, stream>>>(x, emb, Ahi, Alo);
  {
    int nwords = (107085824 - 105906176) / 4;  // state block words
    k_zero<<<(nwords + 255) / 256, 256, 0, stream>>>((uint32_t*)(ws + 105906176), nwords);
  }
  k_rseq<<<(L_ * B_) / 256, 256, 0, stream>>>(gum, rseq);
  k_pe<<<(L_ * B_) / 256, 256, 0, stream>>>(x, emb, Wp, Pe);

  // ---- sequential scan: 2 kernels per step (kernel boundary = grid sync) ----
  for (int t = 0; t < L_; ++t) {
    k_step_gemm<<<576, 64, 0, stream>>>(Ahi, Alo, h_hi, h_lo, hs_hi, hs_lo,
                                        Wl_hi, Wl_lo, Ws_hi, Ws_lo, part, t);
    k_step_point<<<256, 256, 0, stream>>>(part, c_l, h_f, h_hi, h_lo, c_s, hs_hi, hs_lo,
                                          p_acc, rseq, bihl, bhhl, bihs, bhhs,
                                          Wp, out_h, t);
  }

  // ---- epilogue ----
  k_cls1<<<(B_ * 512) / 256, 256, 0, stream>>>(h_f, Wc1, bc1, z1);
  k_cls2<<<B_, 64, 0, stream>>>(z1, Wc2, bc2, out_logits);
  k_pfinal<<<(B_ * L_) / 256, 256, 0, stream>>>(p_acc, Pe, bp, out_p);
}